// Round 3
// baseline (4783.531 us; speedup 1.0000x reference)
//
#include <hip/hip_runtime.h>
#include <stdint.h>

#define V_  32000
#define E_  1024
#define H_  1024
#define B_  64
#define T_  128
#define MROWS (T_ * B_)      // 8192
#define NCB 250              // 32000 / 128 vocab chunks
#define NBLK 128             // persistent recurrence blocks

typedef __bf16 bf16x8 __attribute__((ext_vector_type(8)));
typedef float  f32x4  __attribute__((ext_vector_type(4)));

__device__ __forceinline__ uint16_t f2b(float f) {
  uint32_t u = __builtin_bit_cast(uint32_t, f);
  return (uint16_t)((u + 0x7fffu + ((u >> 16) & 1u)) >> 16);
}
__device__ __forceinline__ float b2f(uint16_t h) {
  uint32_t u = ((uint32_t)h) << 16;
  return __builtin_bit_cast(float, u);
}
__device__ __forceinline__ float sigmoidf_(float x) { return 1.0f / (1.0f + expf(-x)); }

__device__ __forceinline__ void gload16(const uint16_t* g, uint16_t* l) {
  __builtin_amdgcn_global_load_lds(
      (const __attribute__((address_space(1))) uint32_t*)g,
      (__attribute__((address_space(3))) uint32_t*)l,
      16, 0, 0);
}

// ---------------- setup kernels ----------------

__global__ void k_cvt(const float* __restrict__ src, uint16_t* __restrict__ dst, int n4) {
  int i = blockIdx.x * blockDim.x + threadIdx.x;
  int st = gridDim.x * blockDim.x;
  for (; i < n4; i += st) {
    float4 v = ((const float4*)src)[i];
    ushort4 o;
    o.x = f2b(v.x); o.y = f2b(v.y); o.z = f2b(v.z); o.w = f2b(v.w);
    ((ushort4*)dst)[i] = o;
  }
}

// src (R x C) f32 -> dst[col * dstStride + dstOff + row] bf16 (transpose-convert)
__global__ void k_tcvt(const float* __restrict__ src, uint16_t* __restrict__ dst,
                       int R, int C, int dstStride, int dstOff) {
  __shared__ float tile[32][33];
  int c0 = blockIdx.x * 32, r0 = blockIdx.y * 32;
  int tx = threadIdx.x, ty = threadIdx.y;  // (32,8)
  for (int j = 0; j < 32; j += 8)
    tile[ty + j][tx] = src[(size_t)(r0 + ty + j) * C + c0 + tx];
  __syncthreads();
  for (int j = 0; j < 32; j += 8)
    dst[(size_t)(c0 + ty + j) * dstStride + dstOff + r0 + tx] = f2b(tile[tx][ty + j]);
}

__global__ void k_zero(uint4* p, int n) {
  int i = blockIdx.x * blockDim.x + threadIdx.x;
  int st = gridDim.x * blockDim.x;
  uint4 z = {0, 0, 0, 0};
  for (; i < n; i += st) p[i] = z;
}

// ---------------- persistent recurrence kernel ----------------
// Block i owns units u0=i*8..u0+7 (x 4 gates = 32 cols). Weights for those cols
// (K=2048: emb-part then h-part) live in LDS for all 128 steps. c/h state for the
// owned units live in registers. Steps separated by a device-scope atomic barrier.
__global__ __launch_bounds__(256) void k_rec(
    const int* __restrict__ data, const uint16_t* __restrict__ embB,
    const uint16_t* __restrict__ Wcat,   // [4096 cols][2048 k] bf16
    const float* __restrict__ bias, const float* __restrict__ mask,
    uint16_t* __restrict__ hAll, uint32_t* __restrict__ barCnt)
{
  __shared__ uint16_t wLDS[32 * 2048];   // 128 KB, XOR-swizzled rows
  __shared__ float gbuf[B_][32];         // 8 KB gate exchange

  int tid = threadIdx.x;
  int u0 = blockIdx.x * 8;

  // ---- one-time: stage the 32 weight columns into LDS (swizzled) ----
  for (int it = 0; it < 32; ++it) {
    int ch = it * 256 + tid;             // 8192 chunks of 16B
    int c  = ch >> 8;                    // local col 0..31
    int kb = (ch & 255) * 16;            // byte offset within 4096B row
    int gRow = ((c >> 3) * 1024) + u0 + (c & 7);   // gate-major Wcat row
    uint4 v = *(const uint4*)((const char*)(Wcat + (size_t)gRow * 2048) + kb);
    *(uint4*)((char*)wLDS + c * 4096 + (kb ^ ((c & 7) << 4))) = v;
  }

  int w = tid >> 6, l = tid & 63, lr = l & 15, lg = l >> 4;
  int xr = (lr & 7) << 4;                // swizzle XOR (same for both N-tiles)
  const char* wb0 = (const char*)wLDS + (size_t)lr * 4096;
  const char* wb1 = (const char*)wLDS + (size_t)(16 + lr) * 4096;

  // pointwise identity: thread -> unit pu, batch rows pb and pb+32
  int pu = tid & 7, pb = tid >> 3;
  float bI = bias[u0 + pu];
  float bF = bias[1024 + u0 + pu];
  float bG = bias[2048 + u0 + pu];
  float bO = bias[3072 + u0 + pu];
  float cR[2] = {0.f, 0.f}, hR[2] = {0.f, 0.f};

  __syncthreads();

  for (int t = 0; t < T_; ++t) {
    int brow = 16 * w + lr;
    int tok = data[t * B_ + brow];
    const uint16_t* aE = embB + (size_t)tok * E_ + lg * 8;
    const uint16_t* aH = hAll + (size_t)t * (B_ * H_) + (size_t)brow * H_ + lg * 8;

    f32x4 acc0 = {0.f, 0.f, 0.f, 0.f}, acc1 = {0.f, 0.f, 0.f, 0.f};
#pragma unroll 8
    for (int ks = 0; ks < 32; ++ks) {    // emb part (k 0..1023)
      bf16x8 a  = *(const bf16x8*)(aE + ks * 32);
      int ko = (lg * 16 + ks * 64) ^ xr;
      bf16x8 b0 = *(const bf16x8*)(wb0 + ko);
      bf16x8 b1 = *(const bf16x8*)(wb1 + ko);
      acc0 = __builtin_amdgcn_mfma_f32_16x16x32_bf16(a, b0, acc0, 0, 0, 0);
      acc1 = __builtin_amdgcn_mfma_f32_16x16x32_bf16(a, b1, acc1, 0, 0, 0);
    }
#pragma unroll 8
    for (int ks = 0; ks < 32; ++ks) {    // h part (k 1024..2047)
      bf16x8 a  = *(const bf16x8*)(aH + ks * 32);
      int ko = 2048 + ((lg * 16 + ks * 64) ^ xr);
      bf16x8 b0 = *(const bf16x8*)(wb0 + ko);
      bf16x8 b1 = *(const bf16x8*)(wb1 + ko);
      acc0 = __builtin_amdgcn_mfma_f32_16x16x32_bf16(a, b0, acc0, 0, 0, 0);
      acc1 = __builtin_amdgcn_mfma_f32_16x16x32_bf16(a, b1, acc1, 0, 0, 0);
    }

    // scatter gate pre-activations to LDS: C layout col=lr, row=lg*4+r
#pragma unroll
    for (int r = 0; r < 4; ++r) {
      gbuf[16 * w + lg * 4 + r][lr]      = acc0[r];
      gbuf[16 * w + lg * 4 + r][16 + lr] = acc1[r];
    }
    __syncthreads();

    // pointwise LSTM for owned units; c/h in registers
#pragma unroll
    for (int j = 0; j < 2; ++j) {
      int b = pb + 32 * j;
      float gi = sigmoidf_(gbuf[b][pu]      + bI);
      float gf = sigmoidf_(gbuf[b][8 + pu]  + bF);
      float gg = tanhf    (gbuf[b][16 + pu] + bG);
      float go = sigmoidf_(gbuf[b][24 + pu] + bO);
      float mm = mask[(t + 1) * B_ + b];
      float cn = gf * cR[j] + gi * gg;
      float hn = go * tanhf(cn);
      cR[j] = mm * cn + (1.f - mm) * cR[j];
      hR[j] = mm * hn + (1.f - mm) * hR[j];
      hAll[(size_t)(t + 1) * (B_ * H_) + (size_t)b * H_ + u0 + pu] = f2b(hR[j]);
    }

    if (t != T_ - 1) {
      // device-scope grid barrier (monotonic counter, fresh target per step)
      __threadfence();
      __syncthreads();
      if (tid == 0) {
        __hip_atomic_fetch_add(barCnt, 1u, __ATOMIC_ACQ_REL, __HIP_MEMORY_SCOPE_AGENT);
        uint32_t target = (uint32_t)(t + 1) * NBLK;
        while (__hip_atomic_load(barCnt, __ATOMIC_ACQUIRE, __HIP_MEMORY_SCOPE_AGENT) < target) {
          __builtin_amdgcn_s_sleep(2);
        }
      }
      __syncthreads();
      __threadfence();
    }
  }
}

// ---------------- batched projection: out[t*B+b][e] = h[t+1][b] . Wr[e] + br[e] ----------------
__global__ __launch_bounds__(256) void k_out(
    const uint16_t* __restrict__ hAll, const uint16_t* __restrict__ WrB,
    const float* __restrict__ br, uint16_t* __restrict__ outAll)
{
  int tid = threadIdx.x, w = tid >> 6, l = tid & 63, lr = l & 15, lg = l >> 4;
  int t = blockIdx.y;
  int e0 = blockIdx.x * 64;
  const uint16_t* aRow = hAll + ((size_t)(t + 1) * B_ + 16 * w + lr) * H_ + lg * 8;
  f32x4 acc[4] = {};
#pragma unroll 2
  for (int ks = 0; ks < 32; ++ks) {
    bf16x8 a = *(const bf16x8*)(aRow + ks * 32);
#pragma unroll
    for (int n = 0; n < 4; ++n) {
      bf16x8 bb = *(const bf16x8*)(WrB + (size_t)(e0 + n * 16 + lr) * H_ + lg * 8 + ks * 32);
      acc[n] = __builtin_amdgcn_mfma_f32_16x16x32_bf16(a, bb, acc[n], 0, 0, 0);
    }
  }
  int bb_ = 16 * w + lg * 4;
#pragma unroll
  for (int n = 0; n < 4; ++n) {
    int e = e0 + n * 16 + lr;
    float brv = br[e];
#pragma unroll
    for (int r = 0; r < 4; ++r)
      outAll[((size_t)t * B_ + bb_ + r) * E_ + e] = f2b(acc[n][r] + brv);
  }
}

// ---------------- big logits GEMM (m97 structure) + softmax partials ----------------
__global__ __launch_bounds__(256) void k_logits2(
    const uint16_t* __restrict__ A, const uint16_t* __restrict__ Bm,
    const float* __restrict__ bd, float2* __restrict__ part)
{
  __shared__ uint16_t lA[128 * 64];
  __shared__ uint16_t lB[128 * 64];
  __shared__ float2 cm[2][128];

  int tid = threadIdx.x;
  int w = tid >> 6, l = tid & 63, lr = l & 15, lg = l >> 4;
  int wr = w >> 1, wc = w & 1;
  int m0 = blockIdx.x * 128;
  int n0 = blockIdx.y * 128;

  int stRow = l >> 3;
  int kswz  = ((l & 7) * 8) ^ ((stRow & 7) << 3);
  const uint16_t* aSrc = A  + (size_t)(m0 + w * 32 + stRow) * 1024 + kswz;
  const uint16_t* bSrc = Bm + (size_t)(n0 + w * 32 + stRow) * 1024 + kswz;

  f32x4 acc[4][4] = {};

  for (int kt = 0; kt < 1024; kt += 64) {
#pragma unroll
    for (int cc = 0; cc < 4; ++cc) {
      gload16(aSrc + (size_t)cc * 8 * 1024 + kt, &lA[(w * 4 + cc) * 512]);
      gload16(bSrc + (size_t)cc * 8 * 1024 + kt, &lB[(w * 4 + cc) * 512]);
    }
    __syncthreads();
#pragma unroll
    for (int ksub = 0; ksub < 2; ++ksub) {
      bf16x8 af[4], bf[4];
      int ke = ksub * 32 + lg * 8;
#pragma unroll
      for (int mi = 0; mi < 4; ++mi) {
        int row = wr * 64 + mi * 16 + lr;
        af[mi] = *(const bf16x8*)&lA[row * 64 + (ke ^ ((row & 7) << 3))];
      }
#pragma unroll
      for (int ni = 0; ni < 4; ++ni) {
        int row = wc * 64 + ni * 16 + lr;
        bf[ni] = *(const bf16x8*)&lB[row * 64 + (ke ^ ((row & 7) << 3))];
      }
#pragma unroll
      for (int mi = 0; mi < 4; ++mi)
#pragma unroll
        for (int ni = 0; ni < 4; ++ni)
          acc[mi][ni] = __builtin_amdgcn_mfma_f32_16x16x32_bf16(af[mi], bf[ni], acc[mi][ni], 0, 0, 0);
    }
    __syncthreads();
  }

  float bdv[4];
#pragma unroll
  for (int ni = 0; ni < 4; ++ni) bdv[ni] = bd[n0 + wc * 64 + ni * 16 + lr];
#pragma unroll
  for (int mi = 0; mi < 4; ++mi) {
#pragma unroll
    for (int r = 0; r < 4; ++r) {
      float mx = -1e30f;
#pragma unroll
      for (int ni = 0; ni < 4; ++ni) { acc[mi][ni][r] += bdv[ni]; mx = fmaxf(mx, acc[mi][ni][r]); }
#pragma unroll
      for (int d = 1; d < 16; d <<= 1) mx = fmaxf(mx, __shfl_xor(mx, d, 64));
      float s = 0.f;
#pragma unroll
      for (int ni = 0; ni < 4; ++ni) s += expf(acc[mi][ni][r] - mx);
#pragma unroll
      for (int d = 1; d < 16; d <<= 1) s += __shfl_xor(s, d, 64);
      if (lr == 0) cm[wc][wr * 64 + mi * 16 + lg * 4 + r] = make_float2(mx, s);
    }
  }
  __syncthreads();
  if (tid < 128) {
    float2 p0 = cm[0][tid], p1 = cm[1][tid];
    float M = fmaxf(p0.x, p1.x);
    float S = p0.y * expf(p0.x - M) + p1.y * expf(p1.x - M);
    part[(size_t)blockIdx.y * MROWS + m0 + tid] = make_float2(M, S);
  }
}

// ---------------- target logits ----------------
__global__ __launch_bounds__(256) void k_tgt(
    const uint16_t* __restrict__ outAll, const uint16_t* __restrict__ embB,
    const float* __restrict__ bd, const int* __restrict__ data, float* __restrict__ tgt)
{
  int w = threadIdx.x >> 6, l = threadIdx.x & 63;
  int row = blockIdx.x * 4 + w;
  int t = row >> 6, b = row & 63;
  int ty = data[(t + 1) * B_ + b];
  const uint16_t* a = outAll + (size_t)row * E_;
  const uint16_t* e = embB + (size_t)ty * E_;
  float s = 0.f;
#pragma unroll
  for (int i0 = 0; i0 < 2; ++i0) {
    int i = (l + i0 * 64) * 8;
    bf16x8 av = *(const bf16x8*)(a + i);
    bf16x8 ev = *(const bf16x8*)(e + i);
#pragma unroll
    for (int j = 0; j < 8; ++j) s += (float)av[j] * (float)ev[j];
  }
#pragma unroll
  for (int d = 1; d < 64; d <<= 1) s += __shfl_xor(s, d, 64);
  if (l == 0) tgt[row] = s + bd[ty];
}

// ---------------- LSE over 250 chunks + NLL per row ----------------
__global__ __launch_bounds__(256) void k_lse(
    const float2* __restrict__ part, const float* __restrict__ tgt,
    const float* __restrict__ mask, float* __restrict__ rowNll)
{
  int w = threadIdx.x >> 6, l = threadIdx.x & 63;
  int row = blockIdx.x * 4 + w;
  float m = -1e30f, s = 0.f;
  for (int cc = l; cc < NCB; cc += 64) {
    float2 v = part[(size_t)cc * MROWS + row];
    float M = fmaxf(m, v.x);
    s = s * expf(m - M) + v.y * expf(v.x - M);
    m = M;
  }
#pragma unroll
  for (int d = 1; d < 64; d <<= 1) {
    float om = __shfl_xor(m, d, 64);
    float os = __shfl_xor(s, d, 64);
    float M = fmaxf(m, om);
    s = s * expf(m - M) + os * expf(om - M);
    m = M;
  }
  if (l == 0) {
    int t = row >> 6, b = row & 63;
    float nll = (m + logf(s)) - tgt[row];
    rowNll[row] = nll * mask[(t + 1) * B_ + b];
  }
}

__global__ void k_final2(const float* __restrict__ rowNll, float* __restrict__ out) {
  __shared__ float red[256];
  float s = 0.f;
  for (int i = threadIdx.x; i < MROWS; i += 256) s += rowNll[i];
  red[threadIdx.x] = s;
  __syncthreads();
  for (int st = 128; st > 0; st >>= 1) {
    if ((int)threadIdx.x < st) red[threadIdx.x] += red[threadIdx.x + st];
    __syncthreads();
  }
  if (threadIdx.x == 0) out[0] = red[0] / (float)(B_ * B_);
}

// ---------------- host ----------------
extern "C" void kernel_launch(void* const* d_in, const int* in_sizes, int n_in,
                              void* d_out, int out_size, void* d_ws, size_t ws_size,
                              hipStream_t stream)
{
  const int*   data = (const int*)  d_in[0];
  const float* mask = (const float*)d_in[1];
  const float* emb  = (const float*)d_in[2];
  const float* W_ih = (const float*)d_in[3];
  const float* W_hh = (const float*)d_in[4];
  const float* bias = (const float*)d_in[5];
  const float* Wr   = (const float*)d_in[6];
  const float* br   = (const float*)d_in[7];
  const float* bd   = (const float*)d_in[8];
  (void)in_sizes; (void)n_in; (void)out_size; (void)ws_size;

  char* ws = (char*)d_ws;
  size_t off = 0;
  auto alloc = [&](size_t bytes) -> char* {
    char* p = ws + off;
    off += (bytes + 255) & ~(size_t)255;
    return p;
  };
  uint16_t* embB   = (uint16_t*)alloc((size_t)V_ * E_ * 2);            // 65.5 MB
  uint16_t* Wcat   = (uint16_t*)alloc((size_t)4 * H_ * 2048 * 2);      // 16.8 MB
  uint16_t* WrB    = (uint16_t*)alloc((size_t)E_ * H_ * 2);            // 2.1 MB
  uint16_t* hAll   = (uint16_t*)alloc((size_t)(T_ + 1) * B_ * H_ * 2); // 16.9 MB
  uint16_t* outAll = (uint16_t*)alloc((size_t)MROWS * E_ * 2);         // 16.8 MB
  float2*   part   = (float2*)  alloc((size_t)NCB * MROWS * 8);        // 16.4 MB
  float*    tgt    = (float*)   alloc((size_t)MROWS * 4);
  float*    rowNll = (float*)   alloc((size_t)MROWS * 4);
  uint32_t* barCnt = (uint32_t*)alloc(256);

  // one-time conversions
  k_cvt <<<2048, 256, 0, stream>>>(emb, embB, V_ * E_ / 4);
  k_cvt <<<256,  256, 0, stream>>>(Wr, WrB, E_ * H_ / 4);
  k_tcvt<<<dim3(4 * H_ / 32, E_ / 32), dim3(32, 8), 0, stream>>>(W_ih, Wcat, E_, 4 * H_, 2048, 0);
  k_tcvt<<<dim3(4 * H_ / 32, H_ / 32), dim3(32, 8), 0, stream>>>(W_hh, Wcat, H_, 4 * H_, 2048, 1024);
  k_zero<<<32, 256, 0, stream>>>((uint4*)hAll, B_ * H_ * 2 / 16);
  k_zero<<<1, 64, 0, stream>>>((uint4*)barCnt, 1);

  // persistent recurrence (all 128 steps in one kernel)
  k_rec<<<NBLK, 256, 0, stream>>>(data, embB, Wcat, bias, mask, hAll, barCnt);

  // batched projection + big logits GEMM with fused softmax partials
  k_out    <<<dim3(E_ / 64, T_), 256, 0, stream>>>(hAll, WrB, br, outAll);
  k_logits2<<<dim3(MROWS / 128, NCB), 256, 0, stream>>>(outAll, embB, bd, part);
  k_tgt    <<<MROWS / 4, 256, 0, stream>>>(outAll, embB, bd, data, tgt);

  k_lse    <<<MROWS / 4, 256, 0, stream>>>(part, tgt, mask, rowNll);
  k_final2 <<<1, 256, 0, stream>>>(rowNll, (float*)d_out);
}

// Round 4
// 3244.341 us; speedup vs baseline: 1.4744x; 1.4744x over previous
//
#include <hip/hip_runtime.h>
#include <stdint.h>

#define V_  32000
#define E_  1024
#define H_  1024
#define B_  64
#define T_  128
#define MROWS (T_ * B_)      // 8192
#define NCB 250              // 32000 / 128 vocab chunks
#define NRB 64               // persistent recurrence blocks

typedef __bf16 bf16x8 __attribute__((ext_vector_type(8)));
typedef float  f32x4  __attribute__((ext_vector_type(4)));

__device__ __forceinline__ uint16_t f2b(float f) {
  uint32_t u = __builtin_bit_cast(uint32_t, f);
  return (uint16_t)((u + 0x7fffu + ((u >> 16) & 1u)) >> 16);
}
__device__ __forceinline__ float b2f(uint16_t h) {
  uint32_t u = ((uint32_t)h) << 16;
  return __builtin_bit_cast(float, u);
}
__device__ __forceinline__ float sigmoidf_(float x) { return 1.0f / (1.0f + expf(-x)); }

__device__ __forceinline__ void gload16(const uint16_t* g, uint16_t* l) {
  __builtin_amdgcn_global_load_lds(
      (const __attribute__((address_space(1))) uint32_t*)g,
      (__attribute__((address_space(3))) uint32_t*)l,
      16, 0, 0);
}

// ---------------- setup kernels ----------------

__global__ void k_cvt(const float* __restrict__ src, uint16_t* __restrict__ dst, int n4) {
  int i = blockIdx.x * blockDim.x + threadIdx.x;
  int st = gridDim.x * blockDim.x;
  for (; i < n4; i += st) {
    float4 v = ((const float4*)src)[i];
    ushort4 o;
    o.x = f2b(v.x); o.y = f2b(v.y); o.z = f2b(v.z); o.w = f2b(v.w);
    ((ushort4*)dst)[i] = o;
  }
}

// src (R x C) f32 -> dst[col * dstStride + dstOff + row] bf16 (transpose-convert)
__global__ void k_tcvt(const float* __restrict__ src, uint16_t* __restrict__ dst,
                       int R, int C, int dstStride, int dstOff) {
  __shared__ float tile[32][33];
  int c0 = blockIdx.x * 32, r0 = blockIdx.y * 32;
  int tx = threadIdx.x, ty = threadIdx.y;  // (32,8)
  for (int j = 0; j < 32; j += 8)
    tile[ty + j][tx] = src[(size_t)(r0 + ty + j) * C + c0 + tx];
  __syncthreads();
  for (int j = 0; j < 32; j += 8)
    dst[(size_t)(c0 + ty + j) * dstStride + dstOff + r0 + tx] = f2b(tile[tx][ty + j]);
}

__global__ void k_zero(uint4* p, int n) {
  int i = blockIdx.x * blockDim.x + threadIdx.x;
  int st = gridDim.x * blockDim.x;
  uint4 z = {0, 0, 0, 0};
  for (; i < n; i += st) p[i] = z;
}

// ---------------- xW precompute: xAll[r][n] = emb[data[r]] . Wih[n] + b[n] ----------------
// m97 structure with A-row gather. Grid (64, 32), 256 thr.
__global__ __launch_bounds__(256) void k_xw(
    const int* __restrict__ data, const uint16_t* __restrict__ embB,
    const uint16_t* __restrict__ Wcat,   // [4096][2048] bf16; emb part at k 0..1023
    const float* __restrict__ bias, uint16_t* __restrict__ xAll)
{
  __shared__ uint16_t lA[128 * 64];
  __shared__ uint16_t lB[128 * 64];

  int tid = threadIdx.x;
  int w = tid >> 6, l = tid & 63, lr = l & 15, lg = l >> 4;
  int wr = w >> 1, wc = w & 1;
  int m0 = blockIdx.x * 128;
  int n0 = blockIdx.y * 128;

  int stRow = l >> 3;
  int kswz  = ((l & 7) * 8) ^ ((stRow & 7) << 3);
  const uint16_t* aSrc[4];
  const uint16_t* bSrc[4];
#pragma unroll
  for (int cc = 0; cc < 4; ++cc) {
    int tok = data[m0 + w * 32 + cc * 8 + stRow];
    aSrc[cc] = embB + (size_t)tok * 1024 + kswz;
    bSrc[cc] = Wcat + (size_t)(n0 + w * 32 + cc * 8 + stRow) * 2048 + kswz;
  }

  f32x4 acc[4][4] = {};

  for (int kt = 0; kt < 1024; kt += 64) {
#pragma unroll
    for (int cc = 0; cc < 4; ++cc) {
      gload16(aSrc[cc] + kt, &lA[(w * 4 + cc) * 512]);
      gload16(bSrc[cc] + kt, &lB[(w * 4 + cc) * 512]);
    }
    __syncthreads();
#pragma unroll
    for (int ksub = 0; ksub < 2; ++ksub) {
      bf16x8 af[4], bfr[4];
      int ke = ksub * 32 + lg * 8;
#pragma unroll
      for (int mi = 0; mi < 4; ++mi) {
        int row = wr * 64 + mi * 16 + lr;
        af[mi] = *(const bf16x8*)&lA[row * 64 + (ke ^ ((row & 7) << 3))];
      }
#pragma unroll
      for (int ni = 0; ni < 4; ++ni) {
        int row = wc * 64 + ni * 16 + lr;
        bfr[ni] = *(const bf16x8*)&lB[row * 64 + (ke ^ ((row & 7) << 3))];
      }
#pragma unroll
      for (int mi = 0; mi < 4; ++mi)
#pragma unroll
        for (int ni = 0; ni < 4; ++ni)
          acc[mi][ni] = __builtin_amdgcn_mfma_f32_16x16x32_bf16(af[mi], bfr[ni], acc[mi][ni], 0, 0, 0);
    }
    __syncthreads();
  }

  float bv[4];
#pragma unroll
  for (int ni = 0; ni < 4; ++ni) bv[ni] = bias[n0 + wc * 64 + ni * 16 + lr];
#pragma unroll
  for (int mi = 0; mi < 4; ++mi)
#pragma unroll
    for (int ni = 0; ni < 4; ++ni) {
      int row = wr * 64 + mi * 16 + lg * 4;
      int col = n0 + wc * 64 + ni * 16 + lr;
#pragma unroll
      for (int r = 0; r < 4; ++r)
        xAll[(size_t)(m0 + row + r) * 4096 + col] = f2b(acc[mi][ni][r] + bv[ni]);
    }
}

// ---------------- persistent recurrence: g = xW + h@W_hh ----------------
// 64 blocks x 512 thr (8 waves: wm=w>>1 rows 16wm.., wn=w&1 cols 32wn..).
// Block owns units u0=blk*16..+15; local col c = j*4 + q (unit j, gate q).
// W_hh^T slice (64 cols x 1024 k = 128KB) staged once in LDS (XOR-swizzled).
// c/h state in registers; pointwise via shfl_xor across 4-lane gate quads.
__global__ __launch_bounds__(512) void k_rec2(
    const uint16_t* __restrict__ xAll, const uint16_t* __restrict__ Wcat,
    const float* __restrict__ mask, uint16_t* __restrict__ hAll,
    uint32_t* __restrict__ flags)
{
  __shared__ uint16_t wh[64 * 1024];   // 128 KB

  int tid = threadIdx.x;
  int blk = blockIdx.x;
  int u0 = blk * 16;

  // stage W_hh^T slice: 8192 16B-chunks / 512 threads = 16 iters
  for (int it = 0; it < 16; ++it) {
    int ch = it * 512 + tid;
    int c  = ch >> 7;                  // local col 0..63
    int kb = (ch & 127) * 16;          // byte offset in 2048B row
    int gRow = (c & 3) * 1024 + u0 + (c >> 2);
    uint4 v = *(const uint4*)((const char*)Wcat + (size_t)gRow * 4096 + 2048 + kb);
    *(uint4*)((char*)wh + c * 2048 + (kb ^ ((c & 7) << 4))) = v;
  }

  int w = tid >> 6, l = tid & 63, lr = l & 15, lg = l >> 4;
  int wm = w >> 1, wn = w & 1;
  int q = lr & 3;

  const char* wb[2];
#pragma unroll
  for (int ni = 0; ni < 2; ++ni)
    wb[ni] = (const char*)wh + (size_t)(wn * 32 + ni * 16 + lr) * 2048;
  int xr = (lr & 7) << 4;

  int gcol[2];
#pragma unroll
  for (int ni = 0; ni < 2; ++ni)
    gcol[ni] = q * 1024 + u0 + wn * 8 + ni * 4 + (lr >> 2);

  float cR[2][4] = {}, hR[2][4] = {};

  __syncthreads();

  for (int t = 0; t < T_; ++t) {
    // prefetch xW + mask (independent of h)
    float xwv[2][4], mm_[4];
#pragma unroll
    for (int ni = 0; ni < 2; ++ni)
#pragma unroll
      for (int r = 0; r < 4; ++r)
        xwv[ni][r] = b2f(xAll[((size_t)t * 64 + wm * 16 + lg * 4 + r) * 4096 + gcol[ni]]);
#pragma unroll
    for (int r = 0; r < 4; ++r)
      mm_[r] = mask[(t + 1) * B_ + wm * 16 + lg * 4 + r];

    const uint16_t* aH = hAll + (size_t)t * (B_ * H_) + (size_t)(wm * 16 + lr) * H_ + lg * 8;

    f32x4 acc0 = {0.f, 0.f, 0.f, 0.f}, acc1 = {0.f, 0.f, 0.f, 0.f};
#pragma unroll 8
    for (int ks = 0; ks < 32; ++ks) {
      bf16x8 a  = *(const bf16x8*)(aH + ks * 32);
      int ko = (ks * 64 + lg * 16) ^ xr;
      bf16x8 b0 = *(const bf16x8*)(wb[0] + ko);
      bf16x8 b1 = *(const bf16x8*)(wb[1] + ko);
      acc0 = __builtin_amdgcn_mfma_f32_16x16x32_bf16(a, b0, acc0, 0, 0, 0);
      acc1 = __builtin_amdgcn_mfma_f32_16x16x32_bf16(a, b1, acc1, 0, 0, 0);
    }

    // pointwise LSTM via 4-lane gate exchange
#pragma unroll
    for (int ni = 0; ni < 2; ++ni) {
      f32x4 accv = ni ? acc1 : acc0;
#pragma unroll
      for (int r = 0; r < 4; ++r) {
        float v0 = accv[r] + xwv[ni][r];
        float v1 = __shfl_xor(v0, 1, 64);
        float v2 = __shfl_xor(v0, 2, 64);
        float v3 = __shfl_xor(v0, 3, 64);
        float gi = (q == 0) ? v0 : (q == 1) ? v1 : (q == 2) ? v2 : v3;
        float gf = (q == 1) ? v0 : (q == 0) ? v1 : (q == 3) ? v2 : v3;
        float gg = (q == 2) ? v0 : (q == 3) ? v1 : (q == 0) ? v2 : v3;
        float go = (q == 3) ? v0 : (q == 2) ? v1 : (q == 1) ? v2 : v3;
        gi = sigmoidf_(gi); gf = sigmoidf_(gf); gg = tanhf(gg); go = sigmoidf_(go);
        float cn = gf * cR[ni][r] + gi * gg;
        float hn = go * tanhf(cn);
        float mm = mm_[r];
        cR[ni][r] = mm * cn + (1.f - mm) * cR[ni][r];
        hR[ni][r] = mm * hn + (1.f - mm) * hR[ni][r];
        if (q == 0)
          hAll[(size_t)(t + 1) * (B_ * H_) +
               (size_t)(wm * 16 + lg * 4 + r) * H_ + u0 + wn * 8 + ni * 4 + (lr >> 2)]
            = f2b(hR[ni][r]);
      }
    }

    if (t != T_ - 1) {
      __syncthreads();                 // h stores issued & drained (vmcnt 0)
      if (tid < 64) {                  // wave 0 only: fence + flags + poll
        __threadfence();
        if (tid == 0)
          __hip_atomic_store(&flags[blk * 32], (uint32_t)(t + 1),
                             __ATOMIC_RELEASE, __HIP_MEMORY_SCOPE_AGENT);
        while (__hip_atomic_load(&flags[tid * 32], __ATOMIC_ACQUIRE,
                                 __HIP_MEMORY_SCOPE_AGENT) < (uint32_t)(t + 1)) {
          __builtin_amdgcn_s_sleep(1);
        }
        __threadfence();
      }
      __syncthreads();
    }
  }
}

// ---------------- batched projection: out[t*B+b][e] = h[t+1][b] . Wr[e] + br[e] ----------------
__global__ __launch_bounds__(256) void k_out(
    const uint16_t* __restrict__ hAll, const uint16_t* __restrict__ WrB,
    const float* __restrict__ br, uint16_t* __restrict__ outAll)
{
  int tid = threadIdx.x, w = tid >> 6, l = tid & 63, lr = l & 15, lg = l >> 4;
  int t = blockIdx.y;
  int e0 = blockIdx.x * 64;
  const uint16_t* aRow = hAll + ((size_t)(t + 1) * B_ + 16 * w + lr) * H_ + lg * 8;
  f32x4 acc[4] = {};
#pragma unroll 2
  for (int ks = 0; ks < 32; ++ks) {
    bf16x8 a = *(const bf16x8*)(aRow + ks * 32);
#pragma unroll
    for (int n = 0; n < 4; ++n) {
      bf16x8 bb = *(const bf16x8*)(WrB + (size_t)(e0 + n * 16 + lr) * H_ + lg * 8 + ks * 32);
      acc[n] = __builtin_amdgcn_mfma_f32_16x16x32_bf16(a, bb, acc[n], 0, 0, 0);
    }
  }
  int bb_ = 16 * w + lg * 4;
#pragma unroll
  for (int n = 0; n < 4; ++n) {
    int e = e0 + n * 16 + lr;
    float brv = br[e];
#pragma unroll
    for (int r = 0; r < 4; ++r)
      outAll[((size_t)t * B_ + bb_ + r) * E_ + e] = f2b(acc[n][r] + brv);
  }
}

// ---------------- big logits GEMM (m97 structure) + softmax partials ----------------
__global__ __launch_bounds__(256) void k_logits2(
    const uint16_t* __restrict__ A, const uint16_t* __restrict__ Bm,
    const float* __restrict__ bd, float2* __restrict__ part)
{
  __shared__ uint16_t lA[128 * 64];
  __shared__ uint16_t lB[128 * 64];
  __shared__ float2 cm[2][128];

  int tid = threadIdx.x;
  int w = tid >> 6, l = tid & 63, lr = l & 15, lg = l >> 4;
  int wr = w >> 1, wc = w & 1;
  int m0 = blockIdx.x * 128;
  int n0 = blockIdx.y * 128;

  int stRow = l >> 3;
  int kswz  = ((l & 7) * 8) ^ ((stRow & 7) << 3);
  const uint16_t* aSrc = A  + (size_t)(m0 + w * 32 + stRow) * 1024 + kswz;
  const uint16_t* bSrc = Bm + (size_t)(n0 + w * 32 + stRow) * 1024 + kswz;

  f32x4 acc[4][4] = {};

  for (int kt = 0; kt < 1024; kt += 64) {
#pragma unroll
    for (int cc = 0; cc < 4; ++cc) {
      gload16(aSrc + (size_t)cc * 8 * 1024 + kt, &lA[(w * 4 + cc) * 512]);
      gload16(bSrc + (size_t)cc * 8 * 1024 + kt, &lB[(w * 4 + cc) * 512]);
    }
    __syncthreads();
#pragma unroll
    for (int ksub = 0; ksub < 2; ++ksub) {
      bf16x8 af[4], bfr[4];
      int ke = ksub * 32 + lg * 8;
#pragma unroll
      for (int mi = 0; mi < 4; ++mi) {
        int row = wr * 64 + mi * 16 + lr;
        af[mi] = *(const bf16x8*)&lA[row * 64 + (ke ^ ((row & 7) << 3))];
      }
#pragma unroll
      for (int ni = 0; ni < 4; ++ni) {
        int row = wc * 64 + ni * 16 + lr;
        bfr[ni] = *(const bf16x8*)&lB[row * 64 + (ke ^ ((row & 7) << 3))];
      }
#pragma unroll
      for (int mi = 0; mi < 4; ++mi)
#pragma unroll
        for (int ni = 0; ni < 4; ++ni)
          acc[mi][ni] = __builtin_amdgcn_mfma_f32_16x16x32_bf16(af[mi], bfr[ni], acc[mi][ni], 0, 0, 0);
    }
    __syncthreads();
  }

  float bdv[4];
#pragma unroll
  for (int ni = 0; ni < 4; ++ni) bdv[ni] = bd[n0 + wc * 64 + ni * 16 + lr];
#pragma unroll
  for (int mi = 0; mi < 4; ++mi) {
#pragma unroll
    for (int r = 0; r < 4; ++r) {
      float mx = -1e30f;
#pragma unroll
      for (int ni = 0; ni < 4; ++ni) { acc[mi][ni][r] += bdv[ni]; mx = fmaxf(mx, acc[mi][ni][r]); }
#pragma unroll
      for (int d = 1; d < 16; d <<= 1) mx = fmaxf(mx, __shfl_xor(mx, d, 64));
      float s = 0.f;
#pragma unroll
      for (int ni = 0; ni < 4; ++ni) s += expf(acc[mi][ni][r] - mx);
#pragma unroll
      for (int d = 1; d < 16; d <<= 1) s += __shfl_xor(s, d, 64);
      if (lr == 0) cm[wc][wr * 64 + mi * 16 + lg * 4 + r] = make_float2(mx, s);
    }
  }
  __syncthreads();
  if (tid < 128) {
    float2 p0 = cm[0][tid], p1 = cm[1][tid];
    float M = fmaxf(p0.x, p1.x);
    float S = p0.y * expf(p0.x - M) + p1.y * expf(p1.x - M);
    part[(size_t)blockIdx.y * MROWS + m0 + tid] = make_float2(M, S);
  }
}

// ---------------- target logits ----------------
__global__ __launch_bounds__(256) void k_tgt(
    const uint16_t* __restrict__ outAll, const uint16_t* __restrict__ embB,
    const float* __restrict__ bd, const int* __restrict__ data, float* __restrict__ tgt)
{
  int w = threadIdx.x >> 6, l = threadIdx.x & 63;
  int row = blockIdx.x * 4 + w;
  int t = row >> 6, b = row & 63;
  int ty = data[(t + 1) * B_ + b];
  const uint16_t* a = outAll + (size_t)row * E_;
  const uint16_t* e = embB + (size_t)ty * E_;
  float s = 0.f;
#pragma unroll
  for (int i0 = 0; i0 < 2; ++i0) {
    int i = (l + i0 * 64) * 8;
    bf16x8 av = *(const bf16x8*)(a + i);
    bf16x8 ev = *(const bf16x8*)(e + i);
#pragma unroll
    for (int j = 0; j < 8; ++j) s += (float)av[j] * (float)ev[j];
  }
#pragma unroll
  for (int d = 1; d < 64; d <<= 1) s += __shfl_xor(s, d, 64);
  if (l == 0) tgt[row] = s + bd[ty];
}

// ---------------- LSE over 250 chunks + NLL per row ----------------
__global__ __launch_bounds__(256) void k_lse(
    const float2* __restrict__ part, const float* __restrict__ tgt,
    const float* __restrict__ mask, float* __restrict__ rowNll)
{
  int w = threadIdx.x >> 6, l = threadIdx.x & 63;
  int row = blockIdx.x * 4 + w;
  float m = -1e30f, s = 0.f;
  for (int cc = l; cc < NCB; cc += 64) {
    float2 v = part[(size_t)cc * MROWS + row];
    float M = fmaxf(m, v.x);
    s = s * expf(m - M) + v.y * expf(v.x - M);
    m = M;
  }
#pragma unroll
  for (int d = 1; d < 64; d <<= 1) {
    float om = __shfl_xor(m, d, 64);
    float os = __shfl_xor(s, d, 64);
    float M = fmaxf(m, om);
    s = s * expf(m - M) + os * expf(om - M);
    m = M;
  }
  if (l == 0) {
    int t = row >> 6, b = row & 63;
    float nll = (m + logf(s)) - tgt[row];
    rowNll[row] = nll * mask[(t + 1) * B_ + b];
  }
}

__global__ void k_final2(const float* __restrict__ rowNll, float* __restrict__ out) {
  __shared__ float red[256];
  float s = 0.f;
  for (int i = threadIdx.x; i < MROWS; i += 256) s += rowNll[i];
  red[threadIdx.x] = s;
  __syncthreads();
  for (int st = 128; st > 0; st >>= 1) {
    if ((int)threadIdx.x < st) red[threadIdx.x] += red[threadIdx.x + st];
    __syncthreads();
  }
  if (threadIdx.x == 0) out[0] = red[0] / (float)(B_ * B_);
}

// ---------------- host ----------------
extern "C" void kernel_launch(void* const* d_in, const int* in_sizes, int n_in,
                              void* d_out, int out_size, void* d_ws, size_t ws_size,
                              hipStream_t stream)
{
  const int*   data = (const int*)  d_in[0];
  const float* mask = (const float*)d_in[1];
  const float* emb  = (const float*)d_in[2];
  const float* W_ih = (const float*)d_in[3];
  const float* W_hh = (const float*)d_in[4];
  const float* bias = (const float*)d_in[5];
  const float* Wr   = (const float*)d_in[6];
  const float* br   = (const float*)d_in[7];
  const float* bd   = (const float*)d_in[8];
  (void)in_sizes; (void)n_in; (void)out_size; (void)ws_size;

  char* ws = (char*)d_ws;
  size_t off = 0;
  auto alloc = [&](size_t bytes) -> char* {
    char* p = ws + off;
    off += (bytes + 255) & ~(size_t)255;
    return p;
  };
  uint16_t* embB   = (uint16_t*)alloc((size_t)V_ * E_ * 2);            // 65.5 MB
  uint16_t* Wcat   = (uint16_t*)alloc((size_t)4 * H_ * 2048 * 2);      // 16.8 MB
  uint16_t* WrB    = (uint16_t*)alloc((size_t)E_ * H_ * 2);            // 2.1 MB
  uint16_t* hAll   = (uint16_t*)alloc((size_t)(T_ + 1) * B_ * H_ * 2); // 16.9 MB
  uint16_t* xAll   = (uint16_t*)alloc((size_t)MROWS * 4096 * 2);       // 67.1 MB
  uint16_t* outAll = (uint16_t*)alloc((size_t)MROWS * E_ * 2);         // 16.8 MB
  float2*   part   = (float2*)  alloc((size_t)NCB * MROWS * 8);        // 16.4 MB
  float*    tgt    = (float*)   alloc((size_t)MROWS * 4);
  float*    rowNll = (float*)   alloc((size_t)MROWS * 4);
  uint32_t* flags  = (uint32_t*)alloc((size_t)NRB * 32 * 4);           // 8 KB

  // one-time conversions
  k_cvt <<<2048, 256, 0, stream>>>(emb, embB, V_ * E_ / 4);
  k_cvt <<<256,  256, 0, stream>>>(Wr, WrB, E_ * H_ / 4);
  k_tcvt<<<dim3(4 * H_ / 32, E_ / 32), dim3(32, 8), 0, stream>>>(W_ih, Wcat, E_, 4 * H_, 2048, 0);
  k_tcvt<<<dim3(4 * H_ / 32, H_ / 32), dim3(32, 8), 0, stream>>>(W_hh, Wcat, H_, 4 * H_, 2048, 1024);
  k_zero<<<32, 256, 0, stream>>>((uint4*)hAll, B_ * H_ * 2 / 16);
  k_zero<<<2, 256, 0, stream>>>((uint4*)flags, NRB * 32 * 4 / 16);

  // xW = emb[x] @ W_ih + b for all (t,b) — one batched GEMM
  k_xw<<<dim3(MROWS / 128, 4096 / 128), 256, 0, stream>>>(data, embB, Wcat, bias, xAll);

  // persistent recurrence (h @ W_hh only)
  k_rec2<<<NRB, 512, 0, stream>>>(xAll, Wcat, mask, hAll, flags);

  // batched projection + big logits GEMM with fused softmax partials
  k_out    <<<dim3(E_ / 64, T_), 256, 0, stream>>>(hAll, WrB, br, outAll);
  k_logits2<<<dim3(MROWS / 128, NCB), 256, 0, stream>>>(outAll, embB, bd, part);
  k_tgt    <<<MROWS / 4, 256, 0, stream>>>(outAll, embB, bd, data, tgt);

  k_lse    <<<MROWS / 4, 256, 0, stream>>>(part, tgt, mask, rowNll);
  k_final2 <<<1, 256, 0, stream>>>(rowNll, (float*)d_out);
}